// Round 11
// baseline (90.574 us; speedup 1.0000x reference)
//
#include <hip/hip_runtime.h>
#include <hip/hip_bf16.h>
#include <math.h>

// Shapes (hard-coded by the problem)
#define B_   128
#define C1_  128
#define C2_  14
#define S_   14
#define K_   3
#define H_   256
#define E_   2

#define HT   64          // h-tile per block
#define NT   4           // n-subtiles of 16
#define XROWS 224        // M rows r = c2*16 + p (p=s+1; p=0,15 zero pads)
// LDS map (fused): xT [226][64] u16 swizzled @0 (28,928 B);
//                  Bt [64][192] u16 swizzled @28,928 (24,576 B);
//                  Cl [64][228] f32 @0 after K-loop (58,368 B).
#define BT_OFF 28928
#define CROW 228

typedef unsigned short u16;
typedef unsigned int   u32;
typedef __attribute__((ext_vector_type(8))) short bf16x8;
typedef __attribute__((ext_vector_type(4))) float f32x4;

// Direct global->LDS DMA, 16 B per lane; LDS dest = wave-uniform base + lane*16.
#define ASYNC16(g, l) __builtin_amdgcn_global_load_lds(                        \
    (const __attribute__((address_space(1))) void*)(g),                        \
    (__attribute__((address_space(3))) void*)(l), 16, 0, 0)

__device__ __forceinline__ u16 f2bf(float f) {  // RNE fp32->bf16
    u32 u = __float_as_uint(f);
    return (u16)((u + 0x7FFF + ((u >> 16) & 1)) >> 16);
}

__device__ __forceinline__ int decode_shift(const int* p) {
    int a = p[0];
    if (a >= -100 && a <= 100 && a != 0) return a;
    float f = __int_as_float(a);
    if (f >= -100.f && f <= 100.f && f == truncf(f) && f != 0.f) return (int)f;
    long long bits = ((long long)p[1] << 32) | (unsigned int)a;
    double d = __longlong_as_double(bits);
    if (d >= -100.0 && d <= 100.0 && d == trunc(d) && d != 0.0) return (int)d;
    return a;
}

// ---------------------------------------------------------------------------
// cvt: x -> xg[b][hf][row(224)][c1-block^swz] bf16 (row stride 64, zero pads),
//      w1 -> wg[g][hf][hl][kk*64 + (blk^swz)*8+j] bf16 (row stride 192).
// Swizzle: physical col-block = logical block ^ (row&7)  [row = LDS row].
// Blocks 0..1023: x (b, hf, row-quarter).  Blocks 1024..1119: w1.
__global__ __launch_bounds__(256) void cvt_kernel(const float* __restrict__ x,
                                                  const float* __restrict__ w1,
                                                  u16* __restrict__ xg,
                                                  u16* __restrict__ wg) {
    const int blk = blockIdx.x;
    const int t   = threadIdx.x;
    if (blk < 1024) {
        __shared__ u16 xl[64 * 50];                  // [c1l][csl], stride 50
        const int b   = blk >> 3;
        const int hf  = (blk >> 2) & 1;
        const int qr  = blk & 3;
        const int cs0 = qr * 49;
        const float* xb = x + (size_t)(b * C1_ + hf * 64) * 196 + cs0;
#pragma unroll
        for (int i = 0; i < 13; ++i) {               // 64 c1 * 49 cs
            int idx = t + 256 * i;
            if (idx < 3136) {
                int c1l = idx / 49, j = idx - c1l * 49;
                xl[c1l * 50 + j] = f2bf(xb[c1l * 196 + j]);
            }
        }
        __syncthreads();
        u16* dst = xg + (size_t)(b * 2 + hf) * (XROWS * 64) + (size_t)qr * 56 * 64;
#pragma unroll
        for (int i = 0; i < 2; ++i) {                // 56 rows * 8 octs
            int task = t + 256 * i;
            if (task < 448) {
                int rr = task >> 3, o = task & 7;
                int row = qr * 56 + rr;
                int p = row & 15;
                uint4 val = make_uint4(0, 0, 0, 0);
                if (p >= 1 && p <= 14) {
                    int csl = (row >> 4) * 14 + p - 1 - cs0;   // in [0,48]
                    u16 v[8];
#pragma unroll
                    for (int j = 0; j < 8; ++j) v[j] = xl[(o * 8 + j) * 50 + csl];
                    val.x = (u32)v[0] | ((u32)v[1] << 16);
                    val.y = (u32)v[2] | ((u32)v[3] << 16);
                    val.z = (u32)v[4] | ((u32)v[5] << 16);
                    val.w = (u32)v[6] | ((u32)v[7] << 16);
                }
                int op = o ^ (row & 7);              // swizzled col-block
                *(uint4*)&dst[rr * 64 + op * 8] = val;   // still one 128 B row
            }
        }
    } else {
        int q = (blk - 1024) * 256 + t;              // [0, 24576) float4s of w1
        float4 v = ((const float4*)w1)[q];
        int i0 = q * 4;
        int c1 = i0 / 768;
        int kk = (i0 - c1 * 768) >> 8;
        int h0 = i0 & 255;
        int hf = c1 >> 6, c1l = c1 & 63;
        int cb0 = c1l >> 3, j = c1l & 7;
        u16 b4[4] = { f2bf(v.x), f2bf(v.y), f2bf(v.z), f2bf(v.w) };
#pragma unroll
        for (int d = 0; d < 4; ++d) {
            int h = h0 + d, g = h >> 6, hl = h & 63;
            int cb = cb0 ^ (hl & 7);                 // swizzled col-block
            wg[(size_t)((g * 2 + hf) * 64 + hl) * 192 + kk * 64 + cb * 8 + j] = b4[d];
        }
    }
}

// ---------------------------------------------------------------------------
// Fused GEMM (16x16x32 bf16 MFMA) + in-LDS double-roll epilogue. Staging via
// global_load_lds (direct DMA, no VGPR round-trip); LDS layouts XOR-swizzled.
__global__ __launch_bounds__(256, 2) void fused_kernel(const u16* __restrict__ xg,
                                                       const float* __restrict__ w0,
                                                       const u16* __restrict__ wg,
                                                       const int* __restrict__ shift_p,
                                                       float* __restrict__ out) {
    __shared__ __align__(16) char lds[58368];
    float* Cl = (float*)lds;           // [64][CROW] f32, valid after K-loop

    // XCD-aware remap: the 4 h-group blocks of one b share an XCD (L2 reuse of xg).
    const int raw  = blockIdx.x;
    const int xcd  = raw & 7;
    const int slot = raw >> 3;          // 0..63
    const int b    = xcd * 16 + (slot & 15);
    const int g    = slot >> 4;
    const int h0   = g * HT;
    const int t    = threadIdx.x;
    const int wave = t >> 6;
    const int lane = t & 63;
    const int quad = lane >> 4;
    const int l15  = lane & 15;
    const int wbase = t & ~63;          // wave-uniform lane-0 index

    f32x4 acc[4][NT];
#pragma unroll
    for (int i = 0; i < 4; ++i)
#pragma unroll
        for (int j = 0; j < NT; ++j) acc[i][j] = (f32x4){0.f, 0.f, 0.f, 0.f};

    for (int hf = 0; hf < 2; ++hf) {
        if (hf) __syncthreads();
        const uint4* xs = (const uint4*)(xg + (size_t)(b * 2 + hf) * (XROWS * 64));
        const uint4* bs = (const uint4*)(wg + (size_t)(g * 2 + hf) * (64 * 192));
#pragma unroll
        for (int i = 0; i < 7; ++i)                 // x: 1792 uint4, linear landing
            ASYNC16(xs + 256 * i + t, lds + (size_t)(256 * i + wbase) * 16);
#pragma unroll
        for (int i = 0; i < 6; ++i)                 // w1: 1536 uint4, linear landing
            ASYNC16(bs + 256 * i + t, lds + BT_OFF + (size_t)(256 * i + wbase) * 16);
        __syncthreads();                            // drains vmcnt

#pragma unroll
        for (int tt = 0; tt < 6; ++tt) {
            const int kk  = tt >> 1;
            const int cbl = (tt & 1) * 4 + quad;           // logical col-block
            const int bsw = (cbl ^ (l15 & 7)) << 4;        // Bt swizzle byte-off
            const int asw = (cbl ^ ((l15 + kk) & 7)) << 4; // xT swizzle byte-off
            bf16x8 bfr[NT];
#pragma unroll
            for (int nc = 0; nc < NT; ++nc)
                bfr[nc] = *(const bf16x8*)(lds + BT_OFF +
                            (nc * 16 + l15) * 384 + kk * 128 + bsw);
#pragma unroll
            for (int mi = 0; mi < 4; ++mi) {
                int mt = wave + mi * 4;
                if (mt < 14) {
                    int row = mt * 16 + l15 + kk;          // r = c2*16+s, + tap
                    bf16x8 af = *(const bf16x8*)(lds + row * 128 + asw);
#pragma unroll
                    for (int nc = 0; nc < NT; ++nc)
                        acc[mi][nc] = __builtin_amdgcn_mfma_f32_16x16x32_bf16(
                            af, bfr[nc], acc[mi][nc], 0, 0, 0);
                }
            }
        }
    }

    __syncthreads();
#pragma unroll
    for (int mi = 0; mi < 4; ++mi) {
        int mt = wave + mi * 4;
        if (mt < 14) {
#pragma unroll
            for (int nc = 0; nc < NT; ++nc) {
                int hl = nc * 16 + l15;
                *(f32x4*)&Cl[hl * CROW + mt * 16 + quad * 4] = acc[mi][nc];
            }
        }
    }
    __syncthreads();

    // Epilogue: 2-tap roll combine (taps n-independent in ep/weight), float4 out
    const int shift = decode_shift(shift_p);
    const int hl = t >> 2, sub = t & 3;
    const int h = h0 + hl;
    int c0[2]; float wv[2];
#pragma unroll
    for (int e = 0; e < 2; ++e) {
        int q = (e - shift) % 28; if (q < 0) q += 28;
        int np0 = q >> 1, ep = q & 1;
        int c = (np0 - shift) % 14; if (c < 0) c += 14;
        c0[e] = c;
        wv[e] = w0[h * 2 + ep];
    }
    const float* Crow = &Cl[hl * CROW];
    float* orow = out + (size_t)(b * H_ + h) * 196;
#pragma unroll
    for (int jj = 0; jj < 13; ++jj) {
        int i = sub + 4 * jj;
        if (i < 49) {
            float tmp[4];
#pragma unroll
            for (int e4 = 0; e4 < 4; ++e4) {
                int idx = 4 * i + e4;
                int n = idx / 14, m = idx - n * 14;
                int cA = c0[0] + n; if (cA >= 14) cA -= 14;
                int cB = c0[1] + n; if (cB >= 14) cB -= 14;
                tmp[e4] = wv[0] * Crow[cA * 16 + m] + wv[1] * Crow[cB * 16 + m];
            }
            *(float4*)&orow[4 * i] = make_float4(tmp[0], tmp[1], tmp[2], tmp[3]);
        }
    }
}

// ---------------------------------------------------------------------------
// Fallback (ws too small — not expected; ws measured ~268 MB).
__global__ __launch_bounds__(256) void t4_fb(const float* __restrict__ x,
                                             const float* __restrict__ w1,
                                             float* __restrict__ t4) {
    __shared__ float xl[C1_][16];
    const int b = blockIdx.x / C2_, c2 = blockIdx.x % C2_, h = threadIdx.x;
    for (int i = h; i < C1_ * S_; i += 256) {
        int c1 = i / S_, s = i % S_;
        xl[c1][s + 1] = x[((size_t)(b * C1_ + c1) * C2_ + c2) * S_ + s];
    }
    if (h < C1_) { xl[h][0] = 0.f; xl[h][15] = 0.f; }
    __syncthreads();
    float acc[S_];
#pragma unroll
    for (int s = 0; s < S_; ++s) acc[s] = 0.f;
    for (int c1 = 0; c1 < C1_; ++c1) {
        float wa = w1[(size_t)(c1 * K_ + 0) * H_ + h];
        float wb = w1[(size_t)(c1 * K_ + 1) * H_ + h];
        float wc = w1[(size_t)(c1 * K_ + 2) * H_ + h];
#pragma unroll
        for (int s = 0; s < S_; ++s)
            acc[s] += wa * xl[c1][s] + wb * xl[c1][s + 1] + wc * xl[c1][s + 2];
    }
    size_t base = ((size_t)(b * H_ + h) * C2_ + c2) * S_;
#pragma unroll
    for (int s = 0; s < S_; ++s) t4[base + s] = acc[s];
}
__global__ __launch_bounds__(224) void out_fb(float* __restrict__ t4,
                                              const float* __restrict__ w0,
                                              const int* __restrict__ shift_p) {
    const int tid = threadIdx.x;
    const int m = tid % S_, hh = tid / S_;
    const int b = blockIdx.x / 16, h = (blockIdx.x % 16) * 16 + hh;
    const int shift = decode_shift(shift_p);
    const size_t colbase = ((size_t)(b * H_ + h) * C2_) * S_ + m;
    float tl[C2_];
#pragma unroll
    for (int c2 = 0; c2 < C2_; ++c2) tl[c2] = t4[colbase + (size_t)c2 * S_];
    const float w0v[2] = { w0[h * 2 + 0], w0[h * 2 + 1] };
    float r[C2_];
#pragma unroll
    for (int n = 0; n < C2_; ++n) {
        float a = 0.f;
#pragma unroll
        for (int e = 0; e < 2; ++e) {
            int q = (2 * n + e - shift) % 28; if (q < 0) q += 28;
            int np = q >> 1, ep = q & 1;
            int c2 = (np - shift) % 14; if (c2 < 0) c2 += 14;
            a += tl[c2] * w0v[ep];
        }
        r[n] = a;
    }
#pragma unroll
    for (int n = 0; n < C2_; ++n) t4[colbase + (size_t)n * S_] = r[n];
}

extern "C" void kernel_launch(void* const* d_in, const int* in_sizes, int n_in,
                              void* d_out, int out_size, void* d_ws, size_t ws_size,
                              hipStream_t stream) {
    const float* x     = (const float*)d_in[0];
    const float* w0    = (const float*)d_in[1];
    const float* w1    = (const float*)d_in[2];
    const int*   shift = (const int*)(n_in > 3 ? d_in[3] : d_in[n_in - 1]);
    for (int i = 0; i < n_in; ++i) {
        int sz = in_sizes[i];
        if (sz == B_ * C1_ * C2_ * S_)      x     = (const float*)d_in[i];
        else if (sz == H_ * E_)             w0    = (const float*)d_in[i];
        else if (sz == C1_ * K_ * H_)       w1    = (const float*)d_in[i];
        else if (sz == 1)                   shift = (const int*)d_in[i];
    }
    float* out = (float*)d_out;

    const size_t NXG = (size_t)B_ * 2 * XROWS * 64;   // 3,670,016 u16
    const size_t NWG = (size_t)4 * 2 * 64 * 192;      //    98,304 u16
    if (ws_size >= (NXG + NWG) * sizeof(u16)) {
        u16* xg = (u16*)d_ws;
        u16* wg = xg + NXG;
        cvt_kernel<<<1024 + 96, 256, 0, stream>>>(x, w1, xg, wg);
        fused_kernel<<<B_ * 4, 256, 0, stream>>>(xg, w0, wg, shift, out);
    } else {
        t4_fb<<<B_ * C2_, 256, 0, stream>>>(x, w1, out);
        out_fb<<<B_ * 16, 224, 0, stream>>>(out, w0, shift);
    }
}

// Round 12
// 87.586 us; speedup vs baseline: 1.0341x; 1.0341x over previous
//
#include <hip/hip_runtime.h>
#include <hip/hip_bf16.h>
#include <math.h>

// Shapes (hard-coded by the problem)
#define B_   128
#define C1_  128
#define C2_  14
#define S_   14
#define K_   3
#define H_   256
#define E_   2

#define HT   64          // h per group (4 groups)
#define NT   4           // n-subtiles of 16
// Per (b,hf,half): compact xT = 121 rows x 64 u16 (row r = c2l*15 + p; p=0 row
// and r=120 are zero pads; content s = p-1). Two c2 windows: {0..7}, {7..13,0}.
#define XR    121
#define XCHUNK (XR * 64)          // 7744 u16 = 968 uint4 = 15,488 B
#define BT_OFF 15488              // Bt: [64][192] u16 = 24,576 B
#define LDS_SZ 40064              // 4 blocks/CU (163840/40064 = 4.09)
#define CROW 116                  // Cl [64][116] f32 = 29,696 B (reused region)

typedef unsigned short u16;
typedef unsigned int   u32;
typedef __attribute__((ext_vector_type(8))) short bf16x8;
typedef __attribute__((ext_vector_type(4))) float f32x4;

#define ASYNC16(g, l) __builtin_amdgcn_global_load_lds(                        \
    (const __attribute__((address_space(1))) void*)(g),                        \
    (__attribute__((address_space(3))) void*)(l), 16, 0, 0)

__device__ __forceinline__ u16 f2bf(float f) {  // RNE fp32->bf16
    u32 u = __float_as_uint(f);
    return (u16)((u + 0x7FFF + ((u >> 16) & 1)) >> 16);
}

__device__ __forceinline__ int decode_shift(const int* p) {
    int a = p[0];
    if (a >= -100 && a <= 100 && a != 0) return a;
    float f = __int_as_float(a);
    if (f >= -100.f && f <= 100.f && f == truncf(f) && f != 0.f) return (int)f;
    long long bits = ((long long)p[1] << 32) | (unsigned int)a;
    double d = __longlong_as_double(bits);
    if (d >= -100.0 && d <= 100.0 && d == trunc(d) && d != 0.0) return (int)d;
    return a;
}

// ---------------------------------------------------------------------------
// cvt: x -> xg[b][hf][half][121][64] bf16, col-blocks XOR-swizzled by (row&7),
//      zero pads baked in.   w1 -> wg[g][hf][hl][kk*64 + (cb^ (hl&7))*8+j].
// Blocks 0..255: x, one per (b,hf), 512 threads. Blocks 256..303: w1.
__global__ __launch_bounds__(512) void cvt_kernel(const float* __restrict__ x,
                                                  const float* __restrict__ w1,
                                                  u16* __restrict__ xg,
                                                  u16* __restrict__ wg) {
    const int blk = blockIdx.x;
    const int t   = threadIdx.x;
    if (blk < 256) {
        __shared__ u16 xl[64 * 200];                 // [c1l][cs], stride 200
        const int b  = blk >> 1;
        const int hf = blk & 1;
        const float4* src = (const float4*)(x + (size_t)(b * C1_ + hf * 64) * 196);
#pragma unroll
        for (int i = 0; i < 7; ++i) {                // 3136 float4, contiguous
            int q = t + 512 * i;
            if (q < 3136) {
                float4 v = src[q];
                int c1l = q / 49, f4 = q - c1l * 49;
                uint2 w;
                w.x = (u32)f2bf(v.x) | ((u32)f2bf(v.y) << 16);
                w.y = (u32)f2bf(v.z) | ((u32)f2bf(v.w) << 16);
                *(uint2*)&xl[c1l * 200 + f4 * 4] = w;
            }
        }
        __syncthreads();
        u16* dst = xg + (size_t)(b * 2 + hf) * (2 * XCHUNK);
#pragma unroll
        for (int i = 0; i < 4; ++i) {                // 2 half * 121 r * 8 o = 1936
            int idx = t + 512 * i;
            if (idx < 1936) {
                int half = idx / 968, rem = idx - half * 968;
                int rr = rem >> 3, o = rem & 7;
                int c2l = rr / 15, p = rr - c2l * 15;
                uint4 val = make_uint4(0, 0, 0, 0);
                if (p != 0 && rr != 120) {
                    int c2g = half * 7 + c2l; if (c2g >= 14) c2g -= 14;
                    int cs = c2g * 14 + p - 1;
                    u16 v[8];
#pragma unroll
                    for (int j = 0; j < 8; ++j) v[j] = xl[(o * 8 + j) * 200 + cs];
                    val.x = (u32)v[0] | ((u32)v[1] << 16);
                    val.y = (u32)v[2] | ((u32)v[3] << 16);
                    val.z = (u32)v[4] | ((u32)v[5] << 16);
                    val.w = (u32)v[6] | ((u32)v[7] << 16);
                }
                int op = o ^ (rr & 7);               // swizzled col-block
                *(uint4*)&dst[(half * XR + rr) * 64 + op * 8] = val;
            }
        }
    } else {
        int q = (blk - 256) * 512 + t;               // [0, 24576) float4s of w1
        float4 v = ((const float4*)w1)[q];
        int i0 = q * 4;
        int c1 = i0 / 768;
        int kk = (i0 - c1 * 768) >> 8;
        int h0 = i0 & 255;
        int hf = c1 >> 6, c1l = c1 & 63;
        int cb0 = c1l >> 3, j = c1l & 7;
        u16 b4[4] = { f2bf(v.x), f2bf(v.y), f2bf(v.z), f2bf(v.w) };
#pragma unroll
        for (int d = 0; d < 4; ++d) {
            int h = h0 + d, g = h >> 6, hl = h & 63;
            int cb = cb0 ^ (hl & 7);
            wg[(size_t)((g * 2 + hf) * 64 + hl) * 192 + kk * 64 + cb * 8 + j] = b4[d];
        }
    }
}

// ---------------------------------------------------------------------------
// Fused GEMM (16x16x32 bf16 MFMA) + 2-tap FIR roll epilogue.
// Block = (b, half, g): computes C for its 8-c2 window (M=112, 7 m-tiles),
// 64 h; epilogue emits the 7 n values whose taps live in the window.
__global__ __launch_bounds__(256, 4) void fused_kernel(const u16* __restrict__ xg,
                                                       const float* __restrict__ w0,
                                                       const u16* __restrict__ wg,
                                                       const int* __restrict__ shift_p,
                                                       float* __restrict__ out) {
    __shared__ __align__(16) char lds[LDS_SZ];
    float* Cl = (float*)lds;            // [64][CROW] f32, valid after K-loop

    const int raw  = blockIdx.x;
    const int u    = raw & 255;         // same u -> same XCD for all 4 g
    const int g    = raw >> 8;
    const int b    = u >> 1;
    const int half = u & 1;
    const int c0   = half * 7;
    const int h0   = g * HT;
    const int t    = threadIdx.x;
    const int wave = t >> 6;
    const int lane = t & 63;
    const int quad = lane >> 4;
    const int l15  = lane & 15;
    const int wbase = t & ~63;

    // per-lane compact A rows: m-tiles mt = wave + 4*mi (skip mt=7)
    int rb[2]; bool vm[2];
#pragma unroll
    for (int mi = 0; mi < 2; ++mi) {
        int mt = wave + 4 * mi;
        vm[mi] = (mt < 7);
        int m = mt * 16 + l15;
        if (m > 111) m = 111;
        rb[mi] = m + m / 14;            // r = c2l*15 + s
    }

    f32x4 acc[2][NT];
#pragma unroll
    for (int i = 0; i < 2; ++i)
#pragma unroll
        for (int j = 0; j < NT; ++j) acc[i][j] = (f32x4){0.f, 0.f, 0.f, 0.f};

    for (int hf = 0; hf < 2; ++hf) {
        if (hf) __syncthreads();
        const uint4* xs = (const uint4*)(xg + ((size_t)(b * 2 + hf) * 2 + half) * XCHUNK);
        const uint4* bs = (const uint4*)(wg + (size_t)(g * 2 + hf) * (64 * 192));
#pragma unroll
        for (int i = 0; i < 4; ++i) {               // 968 uint4
            int idx = t + 256 * i;
            if (idx < 968)
                ASYNC16(xs + idx, lds + (size_t)(256 * i + wbase) * 16);
        }
#pragma unroll
        for (int i = 0; i < 6; ++i)                 // 1536 uint4
            ASYNC16(bs + 256 * i + t, lds + BT_OFF + (size_t)(256 * i + wbase) * 16);
        __syncthreads();                            // drains vmcnt

#pragma unroll
        for (int tt = 0; tt < 6; ++tt) {
            const int kk  = tt >> 1;
            const int cbl = (tt & 1) * 4 + quad;           // logical col-block
            const int bsw = (cbl ^ (l15 & 7)) << 4;
            bf16x8 bfr[NT];
#pragma unroll
            for (int nc = 0; nc < NT; ++nc)
                bfr[nc] = *(const bf16x8*)(lds + BT_OFF +
                            (nc * 16 + l15) * 384 + kk * 128 + bsw);
#pragma unroll
            for (int mi = 0; mi < 2; ++mi) {
                if (vm[mi]) {
                    int row = rb[mi] + kk;                  // <= 120
                    bf16x8 af = *(const bf16x8*)(lds + row * 128 +
                                 ((cbl ^ (row & 7)) << 4));
#pragma unroll
                    for (int nc = 0; nc < NT; ++nc)
                        acc[mi][nc] = __builtin_amdgcn_mfma_f32_16x16x32_bf16(
                            af, bfr[nc], acc[mi][nc], 0, 0, 0);
                }
            }
        }
    }

    __syncthreads();
#pragma unroll
    for (int mi = 0; mi < 2; ++mi) {
        int mt = wave + 4 * mi;
        if (vm[mi]) {
#pragma unroll
            for (int nc = 0; nc < NT; ++nc) {
                int hl = nc * 16 + l15;
                *(f32x4*)&Cl[hl * CROW + mt * 16 + quad * 4] = acc[mi][nc];
            }
        }
    }
    __syncthreads();

    // Epilogue: taps c2p_e(n) = (n - a_e) mod 14; pick A with (A-a_e)%14 in {0,1};
    // block handles n = n0g..n0g+6 (mod 14); tap read = Crow[base_e + p], p=nn*14+m.
    const int shift = decode_shift(shift_p);
    const int hl = t >> 2, sub = t & 3;
    const int h = h0 + hl;
    int aE[2], epE[2];
#pragma unroll
    for (int e = 0; e < 2; ++e) {
        int q = (e - shift) % 28; if (q < 0) q += 28;
        int np0 = q >> 1; epE[e] = q & 1;
        int c2p0 = (np0 - shift) % 14; if (c2p0 < 0) c2p0 += 14;
        aE[e] = (14 - c2p0) % 14;
    }
    int diff = aE[0] - aE[1]; if (diff < 0) diff += 14;
    int A = (diff == 13) ? aE[1] : aE[0];
    int base0 = ((A - aE[0] + 14) % 14) * 14;
    int base1 = ((A - aE[1] + 14) % 14) * 14;
    float wv0 = w0[h * 2 + epE[0]], wv1 = w0[h * 2 + epE[1]];
    int n0g = c0 + A; if (n0g >= 14) n0g -= 14;
    const int o0 = n0g * 14;
    const float* Crow = &Cl[hl * CROW];
    float* orow = out + (size_t)(b * H_ + h) * 196;
#pragma unroll
    for (int i = 0; i < 13; ++i) {
        int j = sub + 4 * i;
        if (j < 49) {
            int p = 2 * j;
            float v0 = wv0 * Crow[base0 + p]     + wv1 * Crow[base1 + p];
            float v1 = wv0 * Crow[base0 + p + 1] + wv1 * Crow[base1 + p + 1];
            int o = o0 + p; if (o >= 196) o -= 196;   // float2 never straddles
            *(float2*)&orow[o] = make_float2(v0, v1);
        }
    }
}

// ---------------------------------------------------------------------------
// Fallback (ws too small — not expected; ws measured ~268 MB).
__global__ __launch_bounds__(256) void t4_fb(const float* __restrict__ x,
                                             const float* __restrict__ w1,
                                             float* __restrict__ t4) {
    __shared__ float xl[C1_][16];
    const int b = blockIdx.x / C2_, c2 = blockIdx.x % C2_, h = threadIdx.x;
    for (int i = h; i < C1_ * S_; i += 256) {
        int c1 = i / S_, s = i % S_;
        xl[c1][s + 1] = x[((size_t)(b * C1_ + c1) * C2_ + c2) * S_ + s];
    }
    if (h < C1_) { xl[h][0] = 0.f; xl[h][15] = 0.f; }
    __syncthreads();
    float acc[S_];
#pragma unroll
    for (int s = 0; s < S_; ++s) acc[s] = 0.f;
    for (int c1 = 0; c1 < C1_; ++c1) {
        float wa = w1[(size_t)(c1 * K_ + 0) * H_ + h];
        float wb = w1[(size_t)(c1 * K_ + 1) * H_ + h];
        float wc = w1[(size_t)(c1 * K_ + 2) * H_ + h];
#pragma unroll
        for (int s = 0; s < S_; ++s)
            acc[s] += wa * xl[c1][s] + wb * xl[c1][s + 1] + wc * xl[c1][s + 2];
    }
    size_t base = ((size_t)(b * H_ + h) * C2_ + c2) * S_;
#pragma unroll
    for (int s = 0; s < S_; ++s) t4[base + s] = acc[s];
}
__global__ __launch_bounds__(224) void out_fb(float* __restrict__ t4,
                                              const float* __restrict__ w0,
                                              const int* __restrict__ shift_p) {
    const int tid = threadIdx.x;
    const int m = tid % S_, hh = tid / S_;
    const int b = blockIdx.x / 16, h = (blockIdx.x % 16) * 16 + hh;
    const int shift = decode_shift(shift_p);
    const size_t colbase = ((size_t)(b * H_ + h) * C2_) * S_ + m;
    float tl[C2_];
#pragma unroll
    for (int c2 = 0; c2 < C2_; ++c2) tl[c2] = t4[colbase + (size_t)c2 * S_];
    const float w0v[2] = { w0[h * 2 + 0], w0[h * 2 + 1] };
    float r[C2_];
#pragma unroll
    for (int n = 0; n < C2_; ++n) {
        float a = 0.f;
#pragma unroll
        for (int e = 0; e < 2; ++e) {
            int q = (2 * n + e - shift) % 28; if (q < 0) q += 28;
            int np = q >> 1, ep = q & 1;
            int c2 = (np - shift) % 14; if (c2 < 0) c2 += 14;
            a += tl[c2] * w0v[ep];
        }
        r[n] = a;
    }
#pragma unroll
    for (int n = 0; n < C2_; ++n) t4[colbase + (size_t)n * S_] = r[n];
}

extern "C" void kernel_launch(void* const* d_in, const int* in_sizes, int n_in,
                              void* d_out, int out_size, void* d_ws, size_t ws_size,
                              hipStream_t stream) {
    const float* x     = (const float*)d_in[0];
    const float* w0    = (const float*)d_in[1];
    const float* w1    = (const float*)d_in[2];
    const int*   shift = (const int*)(n_in > 3 ? d_in[3] : d_in[n_in - 1]);
    for (int i = 0; i < n_in; ++i) {
        int sz = in_sizes[i];
        if (sz == B_ * C1_ * C2_ * S_)      x     = (const float*)d_in[i];
        else if (sz == H_ * E_)             w0    = (const float*)d_in[i];
        else if (sz == C1_ * K_ * H_)       w1    = (const float*)d_in[i];
        else if (sz == 1)                   shift = (const int*)d_in[i];
    }
    float* out = (float*)d_out;

    const size_t NXG = (size_t)B_ * 2 * 2 * XCHUNK;   // 3,964,928 u16
    const size_t NWG = (size_t)4 * 2 * 64 * 192;      //    98,304 u16
    if (ws_size >= (NXG + NWG) * sizeof(u16)) {
        u16* xg = (u16*)d_ws;
        u16* wg = xg + NXG;
        cvt_kernel<<<304, 512, 0, stream>>>(x, w1, xg, wg);
        fused_kernel<<<1024, 256, 0, stream>>>(xg, w0, wg, shift, out);
    } else {
        t4_fb<<<B_ * C2_, 256, 0, stream>>>(x, w1, out);
        out_fb<<<B_ * 16, 224, 0, stream>>>(out, w0, shift);
    }
}